// Round 15
// baseline (312.954 us; speedup 1.0000x reference)
//
#include <hip/hip_runtime.h>
#include <math.h>

#define N_ 2
#define C_ 64
#define D_ 8
#define H_ 96
#define W_ 96
#define S_ (D_*H_*W_)   // 73728
#define HW_ (H_*W_)     // 9216
// padded xproj (f16): [n][z+2 of 12][y+2 of 100][x+2 of 100][64]
#define ZP_ 12
#define YP_ 100
#define XP_ 100
#define NSTR_ (ZP_*YP_*XP_*64)   // 7680000 elements
#define ZS_ (YP_*XP_*64)         // 640000
#define YS_ (XP_*64)             // 6400

typedef __attribute__((ext_vector_type(8))) short short8;
typedef __attribute__((ext_vector_type(4))) float f32x4;
typedef __attribute__((ext_vector_type(2))) __fp16 h2;

union U32H2 { unsigned u; h2 h; unsigned short s[2]; };
__device__ __forceinline__ h2 uAsH2(unsigned u){ U32H2 t; t.u = u; return t.h; }
__device__ __forceinline__ unsigned h2AsU(h2 h){ U32H2 t; t.h = h; return t.u; }

__device__ __forceinline__ float dot2f(unsigned u, h2 w, float acc) {
#if __has_builtin(__builtin_amdgcn_fdot2)
    return __builtin_amdgcn_fdot2(uAsH2(u), w, acc, false);
#else
    h2 v = uAsH2(u);
    return fmaf((float)v.y, (float)w.y, fmaf((float)v.x, (float)w.x, acc));
#endif
}

__device__ __forceinline__ float gelu_fast(float x) {
    float a = 0.7978845608028654f * (x + 0.044715f*x*x*x);
    float E = __expf(2.f*a);
    return x - x * __builtin_amdgcn_rcpf(E + 1.f);
}

__device__ __forceinline__ unsigned short f2bf(float f) {   // RNE bf16
    unsigned u = __float_as_uint(f);
    unsigned r = (u + 0x7fffu + ((u >> 16) & 1u)) >> 16;
    return (unsigned short)r;
}

__device__ __forceinline__ unsigned short f2h(float f) {    // f32 -> f16 bits
    U32H2 t; t.h[0] = (__fp16)f; t.h[1] = (__fp16)0.f; return t.s[0];
}

// prep: W2 = w_out @ w_post^T (f16-transposed), B2; wBg bf16 proj weights; b4f biases
__global__ __launch_bounds__(64) void k_prep(const float* __restrict__ w_out,
        const float* __restrict__ b_out, const float* __restrict__ w_post,
        const float* __restrict__ w_off, const float* __restrict__ b_off,
        const float* __restrict__ w_mask, const float* __restrict__ b_mask,
        float* __restrict__ B2, unsigned short* __restrict__ W2T,
        unsigned short* __restrict__ wBg, float4* __restrict__ b4f) {
    int b = blockIdx.x;      // 0..63  (= core-channel c2)
    int t = threadIdx.x;     // 0..63  (= output o)
    float acc = 0.f;
    for (int c = 0; c < 64; ++c)
        acc = fmaf(w_out[b*64+c], w_post[t*64+c], acc);
    W2T[t*64 + b] = f2h(acc);          // W2T[o][c2] f16
    if (b == 0) {
        float a2 = 0.f;
        for (int c = 0; c < 64; ++c)
            a2 = fmaf(w_post[t*64+c], b_out[c], a2);
        B2[t] = a2;
    }
    {
        int c = b;
        for (int m = t; m < 224; m += 64) {
            float v = 0.f;
            if (m < 216) {
                int u = m >> 2, comp = m & 3;
                if (comp == 3) v = w_mask[c*54 + u];
                else {
                    v = w_off[c*162 + u*3 + comp];
                    if (comp == 0) v *= 0.5f;
                }
            }
            wBg[m*64 + c] = f2bf(v);
        }
    }
    if (b == 1 && t < 54)
        b4f[t] = make_float4(b_off[t*3]*0.5f, b_off[t*3+1], b_off[t*3+2], b_mask[t]);
}

// fused: pre = x @ w_pre^T (fp32, for dw), xprojP = f16(pre @ w_in + b_in) padded
__global__ __launch_bounds__(256) void k_pre_proj(const float* __restrict__ x,
        const float* __restrict__ w_pre, const float* __restrict__ w_in,
        const float* __restrict__ b_in, float* __restrict__ pre,
        unsigned short* __restrict__ xprojP) {
    __shared__ float lx[64][65];    // [c][v] then reused as [v][c2]
    __shared__ float lwa[64][65];   // w_pre [o][c]
    __shared__ float lwb[64][65];   // w_in  [c][o]
    int b = blockIdx.x;
    int n = b / 1152;
    int s0 = (b % 1152) * 64;
    int tid = threadIdx.x;
    for (int idx = tid; idx < 1024; idx += 256) {
        int r = idx >> 4, q4 = (idx & 15) * 4;
        float4 vx = *(const float4*)&x[((size_t)(n*C_ + r))*S_ + s0 + q4];
        lx[r][q4] = vx.x; lx[r][q4+1] = vx.y; lx[r][q4+2] = vx.z; lx[r][q4+3] = vx.w;
        float4 va = *(const float4*)&w_pre[r*64 + q4];
        lwa[r][q4] = va.x; lwa[r][q4+1] = va.y; lwa[r][q4+2] = va.z; lwa[r][q4+3] = va.w;
        float4 vb = *(const float4*)&w_in[r*64 + q4];
        lwb[r][q4] = vb.x; lwb[r][q4+1] = vb.y; lwb[r][q4+2] = vb.z; lwb[r][q4+3] = vb.w;
    }
    __syncthreads();
    int o0 = (tid & 15) * 4;
    int v0 = (tid >> 4) * 4;
    float acc[4][4] = {};
    #pragma unroll 8
    for (int c = 0; c < 64; ++c) {
        float xv[4], wv[4];
        #pragma unroll
        for (int j = 0; j < 4; ++j) { xv[j] = lx[c][v0+j]; wv[j] = lwa[o0+j][c]; }
        #pragma unroll
        for (int vj = 0; vj < 4; ++vj)
            #pragma unroll
            for (int oj = 0; oj < 4; ++oj)
                acc[vj][oj] = fmaf(xv[vj], wv[oj], acc[vj][oj]);
    }
    #pragma unroll
    for (int vj = 0; vj < 4; ++vj) {
        float4 r = make_float4(acc[vj][0], acc[vj][1], acc[vj][2], acc[vj][3]);
        *(float4*)&pre[((size_t)(n*S_ + s0 + v0 + vj))*64 + o0] = r;
    }
    __syncthreads();
    #pragma unroll
    for (int vj = 0; vj < 4; ++vj)
        #pragma unroll
        for (int oj = 0; oj < 4; ++oj)
            lx[v0+vj][o0+oj] = acc[vj][oj];   // lx = pre tile [v][c2]
    __syncthreads();
    float acc2[4][4];
    #pragma unroll
    for (int oj = 0; oj < 4; ++oj) {
        float bo = b_in[o0+oj];
        #pragma unroll
        for (int vj = 0; vj < 4; ++vj) acc2[vj][oj] = bo;
    }
    #pragma unroll 8
    for (int c = 0; c < 64; ++c) {
        float fv[4], wv[4];
        #pragma unroll
        for (int j = 0; j < 4; ++j) { fv[j] = lx[v0+j][c]; wv[j] = lwb[c][o0+j]; }
        #pragma unroll
        for (int vj = 0; vj < 4; ++vj)
            #pragma unroll
            for (int oj = 0; oj < 4; ++oj)
                acc2[vj][oj] = fmaf(fv[vj], wv[oj], acc2[vj][oj]);
    }
    #pragma unroll
    for (int vj = 0; vj < 4; ++vj) {
        int vox = s0 + v0 + vj;      // within image n
        int z = vox / HW_;
        int rem = vox - z*HW_;
        int y = rem / W_;
        int xq = rem - y*W_;
        size_t pw = (size_t)n*NSTR_ + (size_t)(z+2)*ZS_ + (y+2)*YS_ + (xq+2)*64 + o0;
        unsigned lo = h2AsU(__builtin_amdgcn_cvt_pkrtz(acc2[vj][0], acc2[vj][1]));
        unsigned hi = h2AsU(__builtin_amdgcn_cvt_pkrtz(acc2[vj][2], acc2[vj][3]));
        *(uint2*)&xprojP[pw] = make_uint2(lo, hi);
    }
}

// depthwise 3x3x3 + instance-norm partials; 4 channels per thread, float4 loads
__global__ __launch_bounds__(256) void k_dw_stats(const float* __restrict__ pre,
        const float* __restrict__ w_dw, float* __restrict__ dw,
        float* __restrict__ psum, float* __restrict__ pss) {
    __shared__ float4 lwd[27][16];     // [tap][c4]
    __shared__ float4 lsum[16][16];    // [xg][c4]
    __shared__ float4 lssum[16][16];
    int b = blockIdx.x;               // n*D*H + z*H + y  (1536)
    int y = b % H_;
    int z = (b / H_) % D_;
    int n = b / (D_*H_);
    int tid = threadIdx.x;
    if (tid < 27*16) {
        int k = tid >> 4, c4 = tid & 15;
        lwd[k][c4] = make_float4(w_dw[(c4*4+0)*27 + k], w_dw[(c4*4+1)*27 + k],
                                 w_dw[(c4*4+2)*27 + k], w_dw[(c4*4+3)*27 + k]);
    }
    __syncthreads();
    int c4 = tid & 15, xg = tid >> 4;
    const float* preN = pre + (size_t)n*S_*64;
    float4 s4 = make_float4(0,0,0,0), ss4 = make_float4(0,0,0,0);
    for (int xx = 0; xx < 6; ++xx) {
        int xi = xg + xx*16;
        float4 acc = make_float4(0,0,0,0);
        #pragma unroll
        for (int dz = 0; dz < 3; ++dz) {
            int zz = z + dz - 1;
            if (zz < 0 || zz >= D_) continue;
            #pragma unroll
            for (int dy = 0; dy < 3; ++dy) {
                int yy = y + dy - 1;
                if (yy < 0 || yy >= H_) continue;
                int rowb = (zz*HW_ + yy*W_)*64 + c4*4;
                #pragma unroll
                for (int dx = 0; dx < 3; ++dx) {
                    int xn = xi + dx - 1;
                    if ((unsigned)xn < (unsigned)W_) {
                        float4 v = *(const float4*)&preN[rowb + (xn<<6)];
                        float4 w = lwd[dz*9+dy*3+dx][c4];
                        acc.x = fmaf(v.x, w.x, acc.x);
                        acc.y = fmaf(v.y, w.y, acc.y);
                        acc.z = fmaf(v.z, w.z, acc.z);
                        acc.w = fmaf(v.w, w.w, acc.w);
                    }
                }
            }
        }
        *(float4*)&dw[((size_t)n*S_ + z*HW_ + y*W_ + xi)*64 + c4*4] = acc;
        s4.x += acc.x; s4.y += acc.y; s4.z += acc.z; s4.w += acc.w;
        ss4.x = fmaf(acc.x, acc.x, ss4.x); ss4.y = fmaf(acc.y, acc.y, ss4.y);
        ss4.z = fmaf(acc.z, acc.z, ss4.z); ss4.w = fmaf(acc.w, acc.w, ss4.w);
    }
    lsum[xg][c4] = s4; lssum[xg][c4] = ss4;
    __syncthreads();
    if (tid < 64) {
        float s = 0.f, ss = 0.f;
        #pragma unroll
        for (int k = 0; k < 16; ++k) {
            s  += ((const float*)&lsum [k][tid>>2])[tid&3];
            ss += ((const float*)&lssum[k][tid>>2])[tid&3];
        }
        psum[tid*1536 + b] = s;
        pss [tid*1536 + b] = ss;
    }
}

// reduce partials -> mean / rsqrt(var)
__global__ void k_stats2(const float* __restrict__ psum, const float* __restrict__ pss,
                         float* __restrict__ stats) {
    int u = blockIdx.x;               // 0..127
    int n = u >> 6, c = u & 63;
    int l = threadIdx.x;              // 0..63
    float s = 0.f, ss = 0.f;
    #pragma unroll
    for (int k = 0; k < 12; ++k) {
        int row = n*768 + k*64 + l;
        s  += psum[c*1536 + row];
        ss += pss [c*1536 + row];
    }
    #pragma unroll
    for (int o2 = 32; o2 >= 1; o2 >>= 1) {
        s  += __shfl_xor(s, o2);
        ss += __shfl_xor(ss, o2);
    }
    if (l == 0) {
        float inv = 1.f / (float)S_;
        float mean = s * inv;
        float var = ss * inv - mean*mean;
        stats[n*128 + c] = mean;
        stats[n*128 + 64 + c] = rsqrtf(var + 1e-5f);
    }
}

// fused DCN + output GEMM: block = 1z x 4y x 8x = 32 voxels (64 pairs)
__global__ __launch_bounds__(256, 2) void k_dcn(const unsigned short* __restrict__ xprojP,
        const float* __restrict__ dw, const float* __restrict__ stats,
        const unsigned short* __restrict__ wBg, const float4* __restrict__ b4f,
        const unsigned short* __restrict__ W2T, const float* __restrict__ B2,
        const float* __restrict__ xin, const float* __restrict__ gate,
        float* __restrict__ out) {
    __shared__ uint4 descW[27][64];     // phase1: float4 offs; phase2: f16 weight pairs
    __shared__ union {
        unsigned short featB[32][64];   // 1a/1b: bf16 feat (swizzled 16B blocks)
        int cwl[27][64];                // 2a/2b: base element offsets
        unsigned short coreT[32][64];   // phase4: f16 core (swizzled 16B blocks)
    } uS;
    int tid = threadIdx.x;
    // bijective XCD swizzle: 4608 blocks = 8 * 576
    int orig = blockIdx.x;
    int bid = (orig & 7) * 576 + (orig >> 3);
    int x8 = bid % 12;
    int t1 = bid / 12;
    int y4 = t1 % 24;
    int t2 = t1 / 24;                 // 0..15
    int z  = t2 & 7;
    int n  = t2 >> 3;
    int yb = y4*4, xb = x8*8;
    size_t voxBase = (size_t)n*S_ + (size_t)z*HW_ + yb*W_ + xb;
    float4* offsF = (float4*)descW;

    // 1a: feat = gelu(instnorm(dw)) -> bf16 featB[vox][k] (swizzled 16B blocks)
    {
        int c4 = (tid & 15) * 4;
        int vp = tid >> 4;
        #pragma unroll
        for (int j = 0; j < 2; ++j) {
            int vloc = vp*2 + j;
            size_t vox = voxBase + (vloc>>3)*W_ + (vloc & 7);
            float4 v = *(const float4*)&dw[vox*64 + c4];
            float vals[4] = {v.x, v.y, v.z, v.w};
            ushort4 pk;
            unsigned short* pp = (unsigned short*)&pk;
            #pragma unroll
            for (int jj = 0; jj < 4; ++jj) {
                int c = c4 + jj;
                float t = (vals[jj] - stats[n*128+c]) * stats[n*128+64+c];
                pp[jj] = f2bf(gelu_fast(t));
            }
            int off = ((((c4 >> 3) ^ (vloc & 7)) << 3) | (c4 & 7));
            *(ushort4*)&uS.featB[vloc][off] = pk;
        }
    }
    __syncthreads();

    // 1b: MFMA projection. D[224][32] = wBg[224x64] @ featB[64x32]
    {
        int w = tid >> 6;
        int l = tid & 63;
        int lr = l & 15;
        int lq = l >> 4;
        for (int i = 0; i < 7; ++i) {
            int t7 = w*7 + i;
            int mt = t7 >> 1, nt = t7 & 1;
            int vox = nt*16 + lr;
            f32x4 acc = {0.f, 0.f, 0.f, 0.f};
            #pragma unroll
            for (int h = 0; h < 2; ++h) {
                int k0 = h*32 + lq*8;
                short8 af = *(const short8*)&wBg[(mt*16 + lr)*64 + k0];
                int blk = (((k0 >> 3) ^ (vox & 7)) << 3);
                short8 bf = *(const short8*)&uS.featB[vox][blk];
                acc = __builtin_amdgcn_mfma_f32_16x16x32_bf16(af, bf, acc, 0, 0, 0);
            }
            int u = mt*4 + lq;
            if (u < 54) {
                float4 bb = b4f[u];
                int g = (u >= 27) ? 1 : 0;
                int p = u - g*27;
                offsF[p*64 + vox*2 + g] = make_float4(acc[0] + bb.x, acc[1] + bb.y,
                                                      acc[2] + bb.z, acc[3] + bb.w);
            }
        }
    }
    __syncthreads();

    // softmax over taps per pair (64 pairs); logits in regs, write .w dword only
    if (tid < 64) {
        int pair = tid;
        float lg[27];
        float mx = -1e30f;
        #pragma unroll
        for (int p = 0; p < 27; ++p) {
            lg[p] = offsF[p*64 + pair].w;
            mx = fmaxf(mx, lg[p]);
        }
        float ssum = 0.f;
        #pragma unroll
        for (int p = 0; p < 27; ++p) { lg[p] = __expf(lg[p] - mx); ssum += lg[p]; }
        float inv = __builtin_amdgcn_rcpf(ssum);
        #pragma unroll
        for (int p = 0; p < 27; ++p)
            offsF[p*64 + pair].w = lg[p]*inv;
    }
    __syncthreads();

    // 2a: tap descriptors — 4 packed f16 weight pairs + base offset, once per (pair,tap)
    {
        int zm1 = z - 1;
        #pragma unroll
        for (int k = 0; k < 7; ++k) {
            int idx = tid + k*256;
            if (idx < 1728) {
                int pair = idx & 63;
                int p = idx >> 6;
                float4 tp = offsF[p*64 + pair];
                int vloc = pair >> 1, g = pair & 1;
                int yy = vloc >> 3, xx = vloc & 7;
                float zf = (float)(zm1 + p/9) + tp.z;
                float yf = (float)(yb + yy - 1 + (p/3)%3) + tp.y;
                float xf = (float)(xb + xx - 1 + p%3) + tp.x;
                zf = fminf(fmaxf(zf, -1.5f), (float)D_ + 0.5f);
                yf = fminf(fmaxf(yf, -1.5f), (float)H_ + 0.5f);
                xf = fminf(fmaxf(xf, -1.5f), (float)W_ + 0.5f);
                float z0f = floorf(zf), y0f = floorf(yf), x0f = floorf(xf);
                float fz = zf - z0f, fy = yf - y0f, fx = xf - x0f;
                int zi = (int)z0f, yi = (int)y0f, xi = (int)x0f;
                float wz1 = fz * tp.w, wz0 = tp.w - wz1;   // prob folded in
                float wy1 = fy, wy0 = 1.f - fy;
                float wx1 = fx, wx0 = 1.f - fx;
                float w00 = wz0*wy0, w01 = wz0*wy1, w10 = wz1*wy0, w11 = wz1*wy1;
                unsigned u0 = h2AsU(__builtin_amdgcn_cvt_pkrtz(w00*wx0, w00*wx1));
                unsigned u1 = h2AsU(__builtin_amdgcn_cvt_pkrtz(w01*wx0, w01*wx1));
                unsigned u2 = h2AsU(__builtin_amdgcn_cvt_pkrtz(w10*wx0, w10*wx1));
                unsigned u3 = h2AsU(__builtin_amdgcn_cvt_pkrtz(w11*wx0, w11*wx1));
                int cw = zi*ZS_ + yi*YS_ + (xi<<6) + (2*ZS_ + 2*YS_ + 128) + g*32;
                descW[p][pair] = make_uint4(u0, u1, u2, u3);
                uS.cwl[p][pair] = cw;
            }
        }
    }
    __syncthreads();

    // 2b: double-buffered gather, unroll 1 (regalloc-safe): compute A while loading B
    int pair = tid >> 2;              // 0..63
    int vloc = pair >> 1, g = pair & 1;
    int ch4 = (tid & 3) * 8;          // channel offset within group
    const unsigned short* __restrict__ base = xprojP + (size_t)n*NSTR_ + ch4;
    float a0=0.f,a1=0.f,a2=0.f,a3=0.f,a4=0.f,a5=0.f,a6=0.f,a7=0.f;

    uint4 wpA, qa0A, qa1A, qb0A, qb1A, qc0A, qc1A, qd0A, qd1A;
    uint4 wpB, qa0B, qa1B, qb0B, qb1B, qc0B, qc1B, qd0B, qd1B;

    #define LOADT(P, SFX) { \
        wp##SFX = descW[(P)][pair]; \
        int cw_ = uS.cwl[(P)][pair]; \
        const unsigned short* p00_ = base + cw_; \
        const unsigned short* p01_ = p00_ + YS_; \
        const unsigned short* p10_ = p00_ + ZS_; \
        const unsigned short* p11_ = p10_ + YS_; \
        qa0##SFX = *(const uint4*)p00_;  qa1##SFX = *(const uint4*)(p00_ + 64); \
        qb0##SFX = *(const uint4*)p01_;  qb1##SFX = *(const uint4*)(p01_ + 64); \
        qc0##SFX = *(const uint4*)p10_;  qc1##SFX = *(const uint4*)(p10_ + 64); \
        qd0##SFX = *(const uint4*)p11_;  qd1##SFX = *(const uint4*)(p11_ + 64); \
    }
    // perm sel: lo-ch pair = {A.b0,A.b1,B.b0,B.b1} -> 0x01000504 ; hi-ch -> 0x03020706
    #define CP(QA, QB, WH) { \
        a0 = dot2f(__builtin_amdgcn_perm(QA.x, QB.x, 0x01000504u), WH, a0); \
        a1 = dot2f(__builtin_amdgcn_perm(QA.x, QB.x, 0x03020706u), WH, a1); \
        a2 = dot2f(__builtin_amdgcn_perm(QA.y, QB.y, 0x01000504u), WH, a2); \
        a3 = dot2f(__builtin_amdgcn_perm(QA.y, QB.y, 0x03020706u), WH, a3); \
        a4 = dot2f(__builtin_amdgcn_perm(QA.z, QB.z, 0x01000504u), WH, a4); \
        a5 = dot2f(__builtin_amdgcn_perm(QA.z, QB.z, 0x03020706u), WH, a5); \
        a6 = dot2f(__builtin_amdgcn_perm(QA.w, QB.w, 0x01000504u), WH, a6); \
        a7 = dot2f(__builtin_amdgcn_perm(QA.w, QB.w, 0x03020706u), WH, a7); \
    }
    #define COMPT(SFX) { \
        h2 w0_ = uAsH2(wp##SFX.x), w1_ = uAsH2(wp##SFX.y); \
        h2 w2_ = uAsH2(wp##SFX.z), w3_ = uAsH2(wp##SFX.w); \
        CP(qa0##SFX, qa1##SFX, w0_); CP(qb0##SFX, qb1##SFX, w1_); \
        CP(qc0##SFX, qc1##SFX, w2_); CP(qd0##SFX, qd1##SFX, w3_); \
    }

    LOADT(0, A);
    #pragma unroll 1
    for (int p = 0; p < 26; p += 2) {
        LOADT(p+1, B);
        COMPT(A);
        LOADT(p+2, A);
        COMPT(B);
    }
    COMPT(A);   // tap 26
    #undef COMPT
    #undef CP
    #undef LOADT
    __syncthreads();   // done reading cwl; reuse union as coreT

    // 3: pack core to f16 into coreT[vox][c] (swizzled 16B blocks)
    {
        unsigned c01 = h2AsU(__builtin_amdgcn_cvt_pkrtz(a0, a1));
        unsigned c23 = h2AsU(__builtin_amdgcn_cvt_pkrtz(a2, a3));
        unsigned c45 = h2AsU(__builtin_amdgcn_cvt_pkrtz(a4, a5));
        unsigned c67 = h2AsU(__builtin_amdgcn_cvt_pkrtz(a6, a7));
        int col = g*32 + ch4;
        int blk = (((col >> 3) ^ (vloc & 7)) << 3);
        *(uint4*)&uS.coreT[vloc][blk] = make_uint4(c01, c23, c45, c67);
    }
    __syncthreads();

    // 4: output GEMM via MFMA: out[32 vox][64 o] = coreT @ W2T^T ; +bias, +residual
    {
        int w = tid >> 6, l = tid & 63, lr = l & 15, lq = l >> 4;
        float sg = 1.f / (1.f + __expf(-gate[0]));
        #pragma unroll
        for (int t = 0; t < 2; ++t) {
            int tile = w*2 + t;
            int mt = tile >> 2, nt = tile & 3;
            int o = nt*16 + lr;
            f32x4 acc = {0.f, 0.f, 0.f, 0.f};
            #pragma unroll
            for (int h = 0; h < 2; ++h) {
                int k0 = h*32 + lq*8;
                int arow = mt*16 + lr;
                int blk = (((k0 >> 3) ^ (arow & 7)) << 3);
                short8 af = *(const short8*)&uS.coreT[arow][blk];
                short8 bf = *(const short8*)&W2T[o*64 + k0];
                acc = __builtin_amdgcn_mfma_f32_16x16x32_f16(af, bf, acc, 0, 0, 0);
            }
            float b2 = B2[o];
            int vox0 = mt*16 + lq*4;
            int yy = vox0 >> 3, xx0 = vox0 & 7;
            size_t gi = ((size_t)(n*64 + o))*S_ + (size_t)z*HW_ + (size_t)(yb+yy)*W_ + (xb+xx0);
            float4 xv = *(const float4*)&xin[gi];
            float4 r;
            r.x = fmaf(sg, acc[0] + b2, xv.x);
            r.y = fmaf(sg, acc[1] + b2, xv.y);
            r.z = fmaf(sg, acc[2] + b2, xv.z);
            r.w = fmaf(sg, acc[3] + b2, xv.w);
            *(float4*)&out[gi] = r;
        }
    }
}

extern "C" void kernel_launch(void* const* d_in, const int* in_sizes, int n_in,
                              void* d_out, int out_size, void* d_ws, size_t ws_size,
                              hipStream_t stream) {
    const float* x      = (const float*)d_in[0];
    const float* w_pre  = (const float*)d_in[1];
    const float* w_in   = (const float*)d_in[2];
    const float* b_in   = (const float*)d_in[3];
    const float* w_dw   = (const float*)d_in[4];
    const float* w_off  = (const float*)d_in[5];
    const float* b_off  = (const float*)d_in[6];
    const float* w_mask = (const float*)d_in[7];
    const float* b_mask = (const float*)d_in[8];
    const float* w_out  = (const float*)d_in[9];
    const float* b_out  = (const float*)d_in[10];
    const float* w_post = (const float*)d_in[11];
    const float* gate   = (const float*)d_in[12];
    float* out = (float*)d_out;

    float* ws      = (float*)d_ws;
    unsigned short* xprojP = (unsigned short*)ws;      // 15,360,000 ushorts (30.7MB)
    float* pre     = ws + (size_t)7680000;             // 9,437,184 floats
    float* dwb     = pre + (size_t)9437184;            // 9,437,184 floats (dw scratch)
    float* psum    = dwb + (size_t)9437184;            // 98,304
    float* pss     = psum + 98304;                     // 98,304
    float* stats   = pss + 98304;                      // 256
    float* B2      = stats + 256;                      // 64 (+pad)
    unsigned short* W2T = (unsigned short*)(B2 + 128); // 64*64 ushorts
    unsigned short* wBg = W2T + 4096;                  // 224*64 ushorts
    float4* b4f    = (float4*)(wBg + 14336 + 64);      // 54 float4

    (void)hipMemsetAsync(xprojP, 0, (size_t)15360000*sizeof(unsigned short), stream);
    hipLaunchKernelGGL(k_prep,     dim3(64),   dim3(64),  0, stream,
                       w_out, b_out, w_post, w_off, b_off, w_mask, b_mask,
                       B2, W2T, wBg, b4f);
    hipLaunchKernelGGL(k_pre_proj, dim3(2304), dim3(256), 0, stream,
                       x, w_pre, w_in, b_in, pre, xprojP);
    hipLaunchKernelGGL(k_dw_stats, dim3(1536), dim3(256), 0, stream,
                       pre, w_dw, dwb, psum, pss);
    hipLaunchKernelGGL(k_stats2,   dim3(128),  dim3(64),  0, stream, psum, pss, stats);
    hipLaunchKernelGGL(k_dcn,      dim3(4608), dim3(256), 0, stream,
                       xprojP, dwb, stats, wBg, b4f, W2T, B2, x, gate, out);
}

// Round 16
// 305.516 us; speedup vs baseline: 1.0243x; 1.0243x over previous
//
#include <hip/hip_runtime.h>
#include <math.h>

#define N_ 2
#define C_ 64
#define D_ 8
#define H_ 96
#define W_ 96
#define S_ (D_*H_*W_)   // 73728
#define HW_ (H_*W_)     // 9216
// padded xproj (f16): [n][z+2 of 12][y+2 of 100][x+2 of 100][64]
#define ZP_ 12
#define YP_ 100
#define XP_ 100
#define NSTR_ (ZP_*YP_*XP_*64)   // 7680000 elements
#define ZS_ (YP_*XP_*64)         // 640000
#define YS_ (XP_*64)             // 6400

typedef __attribute__((ext_vector_type(8))) short short8;
typedef __attribute__((ext_vector_type(4))) float f32x4;
typedef __attribute__((ext_vector_type(2))) __fp16 h2;
typedef __attribute__((ext_vector_type(4))) unsigned u32x4;

union U32H2 { unsigned u; h2 h; unsigned short s[2]; };
__device__ __forceinline__ h2 uAsH2(unsigned u){ U32H2 t; t.u = u; return t.h; }
__device__ __forceinline__ unsigned h2AsU(h2 h){ U32H2 t; t.h = h; return t.u; }

__device__ __forceinline__ float dot2f(unsigned u, h2 w, float acc) {
#if __has_builtin(__builtin_amdgcn_fdot2)
    return __builtin_amdgcn_fdot2(uAsH2(u), w, acc, false);
#else
    h2 v = uAsH2(u);
    return fmaf((float)v.y, (float)w.y, fmaf((float)v.x, (float)w.x, acc));
#endif
}

__device__ __forceinline__ float gelu_fast(float x) {
    float a = 0.7978845608028654f * (x + 0.044715f*x*x*x);
    float E = __expf(2.f*a);
    return x - x * __builtin_amdgcn_rcpf(E + 1.f);
}

__device__ __forceinline__ unsigned short f2bf(float f) {   // RNE bf16
    unsigned u = __float_as_uint(f);
    unsigned r = (u + 0x7fffu + ((u >> 16) & 1u)) >> 16;
    return (unsigned short)r;
}

__device__ __forceinline__ unsigned short f2h(float f) {    // f32 -> f16 bits
    U32H2 t; t.h[0] = (__fp16)f; t.h[1] = (__fp16)0.f; return t.s[0];
}

// prep: W2 = w_out @ w_post^T (f16-transposed), B2; wBg bf16 proj weights; b4f biases
__global__ __launch_bounds__(64) void k_prep(const float* __restrict__ w_out,
        const float* __restrict__ b_out, const float* __restrict__ w_post,
        const float* __restrict__ w_off, const float* __restrict__ b_off,
        const float* __restrict__ w_mask, const float* __restrict__ b_mask,
        float* __restrict__ B2, unsigned short* __restrict__ W2T,
        unsigned short* __restrict__ wBg, float4* __restrict__ b4f) {
    int b = blockIdx.x;      // 0..63  (= core-channel c2)
    int t = threadIdx.x;     // 0..63  (= output o)
    float acc = 0.f;
    for (int c = 0; c < 64; ++c)
        acc = fmaf(w_out[b*64+c], w_post[t*64+c], acc);
    W2T[t*64 + b] = f2h(acc);          // W2T[o][c2] f16
    if (b == 0) {
        float a2 = 0.f;
        for (int c = 0; c < 64; ++c)
            a2 = fmaf(w_post[t*64+c], b_out[c], a2);
        B2[t] = a2;
    }
    {
        int c = b;
        for (int m = t; m < 224; m += 64) {
            float v = 0.f;
            if (m < 216) {
                int u = m >> 2, comp = m & 3;
                if (comp == 3) v = w_mask[c*54 + u];
                else {
                    v = w_off[c*162 + u*3 + comp];
                    if (comp == 0) v *= 0.5f;
                }
            }
            wBg[m*64 + c] = f2bf(v);
        }
    }
    if (b == 1 && t < 54)
        b4f[t] = make_float4(b_off[t*3]*0.5f, b_off[t*3+1], b_off[t*3+2], b_mask[t]);
}

// fused: pre = x @ w_pre^T (fp32, for dw), xprojP = f16(pre @ w_in + b_in) padded
__global__ __launch_bounds__(256) void k_pre_proj(const float* __restrict__ x,
        const float* __restrict__ w_pre, const float* __restrict__ w_in,
        const float* __restrict__ b_in, float* __restrict__ pre,
        unsigned short* __restrict__ xprojP) {
    __shared__ float lx[64][65];    // [c][v] then reused as [v][c2]
    __shared__ float lwa[64][65];   // w_pre [o][c]
    __shared__ float lwb[64][65];   // w_in  [c][o]
    int b = blockIdx.x;
    int n = b / 1152;
    int s0 = (b % 1152) * 64;
    int tid = threadIdx.x;
    for (int idx = tid; idx < 1024; idx += 256) {
        int r = idx >> 4, q4 = (idx & 15) * 4;
        float4 vx = *(const float4*)&x[((size_t)(n*C_ + r))*S_ + s0 + q4];
        lx[r][q4] = vx.x; lx[r][q4+1] = vx.y; lx[r][q4+2] = vx.z; lx[r][q4+3] = vx.w;
        float4 va = *(const float4*)&w_pre[r*64 + q4];
        lwa[r][q4] = va.x; lwa[r][q4+1] = va.y; lwa[r][q4+2] = va.z; lwa[r][q4+3] = va.w;
        float4 vb = *(const float4*)&w_in[r*64 + q4];
        lwb[r][q4] = vb.x; lwb[r][q4+1] = vb.y; lwb[r][q4+2] = vb.z; lwb[r][q4+3] = vb.w;
    }
    __syncthreads();
    int o0 = (tid & 15) * 4;
    int v0 = (tid >> 4) * 4;
    float acc[4][4] = {};
    #pragma unroll 8
    for (int c = 0; c < 64; ++c) {
        float xv[4], wv[4];
        #pragma unroll
        for (int j = 0; j < 4; ++j) { xv[j] = lx[c][v0+j]; wv[j] = lwa[o0+j][c]; }
        #pragma unroll
        for (int vj = 0; vj < 4; ++vj)
            #pragma unroll
            for (int oj = 0; oj < 4; ++oj)
                acc[vj][oj] = fmaf(xv[vj], wv[oj], acc[vj][oj]);
    }
    #pragma unroll
    for (int vj = 0; vj < 4; ++vj) {
        float4 r = make_float4(acc[vj][0], acc[vj][1], acc[vj][2], acc[vj][3]);
        *(float4*)&pre[((size_t)(n*S_ + s0 + v0 + vj))*64 + o0] = r;
    }
    __syncthreads();
    #pragma unroll
    for (int vj = 0; vj < 4; ++vj)
        #pragma unroll
        for (int oj = 0; oj < 4; ++oj)
            lx[v0+vj][o0+oj] = acc[vj][oj];   // lx = pre tile [v][c2]
    __syncthreads();
    float acc2[4][4];
    #pragma unroll
    for (int oj = 0; oj < 4; ++oj) {
        float bo = b_in[o0+oj];
        #pragma unroll
        for (int vj = 0; vj < 4; ++vj) acc2[vj][oj] = bo;
    }
    #pragma unroll 8
    for (int c = 0; c < 64; ++c) {
        float fv[4], wv[4];
        #pragma unroll
        for (int j = 0; j < 4; ++j) { fv[j] = lx[v0+j][c]; wv[j] = lwb[c][o0+j]; }
        #pragma unroll
        for (int vj = 0; vj < 4; ++vj)
            #pragma unroll
            for (int oj = 0; oj < 4; ++oj)
                acc2[vj][oj] = fmaf(fv[vj], wv[oj], acc2[vj][oj]);
    }
    #pragma unroll
    for (int vj = 0; vj < 4; ++vj) {
        int vox = s0 + v0 + vj;      // within image n
        int z = vox / HW_;
        int rem = vox - z*HW_;
        int y = rem / W_;
        int xq = rem - y*W_;
        size_t pw = (size_t)n*NSTR_ + (size_t)(z+2)*ZS_ + (y+2)*YS_ + (xq+2)*64 + o0;
        unsigned lo = h2AsU(__builtin_amdgcn_cvt_pkrtz(acc2[vj][0], acc2[vj][1]));
        unsigned hi = h2AsU(__builtin_amdgcn_cvt_pkrtz(acc2[vj][2], acc2[vj][3]));
        *(uint2*)&xprojP[pw] = make_uint2(lo, hi);
    }
}

// depthwise 3x3x3 + instance-norm partials; 4 channels per thread, float4 loads
__global__ __launch_bounds__(256) void k_dw_stats(const float* __restrict__ pre,
        const float* __restrict__ w_dw, float* __restrict__ dw,
        float* __restrict__ psum, float* __restrict__ pss) {
    __shared__ float4 lwd[27][16];     // [tap][c4]
    __shared__ float4 lsum[16][16];    // [xg][c4]
    __shared__ float4 lssum[16][16];
    int b = blockIdx.x;               // n*D*H + z*H + y  (1536)
    int y = b % H_;
    int z = (b / H_) % D_;
    int n = b / (D_*H_);
    int tid = threadIdx.x;
    if (tid < 27*16) {
        int k = tid >> 4, c4 = tid & 15;
        lwd[k][c4] = make_float4(w_dw[(c4*4+0)*27 + k], w_dw[(c4*4+1)*27 + k],
                                 w_dw[(c4*4+2)*27 + k], w_dw[(c4*4+3)*27 + k]);
    }
    __syncthreads();
    int c4 = tid & 15, xg = tid >> 4;
    const float* preN = pre + (size_t)n*S_*64;
    float4 s4 = make_float4(0,0,0,0), ss4 = make_float4(0,0,0,0);
    for (int xx = 0; xx < 6; ++xx) {
        int xi = xg + xx*16;
        float4 acc = make_float4(0,0,0,0);
        #pragma unroll
        for (int dz = 0; dz < 3; ++dz) {
            int zz = z + dz - 1;
            if (zz < 0 || zz >= D_) continue;
            #pragma unroll
            for (int dy = 0; dy < 3; ++dy) {
                int yy = y + dy - 1;
                if (yy < 0 || yy >= H_) continue;
                int rowb = (zz*HW_ + yy*W_)*64 + c4*4;
                #pragma unroll
                for (int dx = 0; dx < 3; ++dx) {
                    int xn = xi + dx - 1;
                    if ((unsigned)xn < (unsigned)W_) {
                        float4 v = *(const float4*)&preN[rowb + (xn<<6)];
                        float4 w = lwd[dz*9+dy*3+dx][c4];
                        acc.x = fmaf(v.x, w.x, acc.x);
                        acc.y = fmaf(v.y, w.y, acc.y);
                        acc.z = fmaf(v.z, w.z, acc.z);
                        acc.w = fmaf(v.w, w.w, acc.w);
                    }
                }
            }
        }
        *(float4*)&dw[((size_t)n*S_ + z*HW_ + y*W_ + xi)*64 + c4*4] = acc;
        s4.x += acc.x; s4.y += acc.y; s4.z += acc.z; s4.w += acc.w;
        ss4.x = fmaf(acc.x, acc.x, ss4.x); ss4.y = fmaf(acc.y, acc.y, ss4.y);
        ss4.z = fmaf(acc.z, acc.z, ss4.z); ss4.w = fmaf(acc.w, acc.w, ss4.w);
    }
    lsum[xg][c4] = s4; lssum[xg][c4] = ss4;
    __syncthreads();
    if (tid < 64) {
        float s = 0.f, ss = 0.f;
        #pragma unroll
        for (int k = 0; k < 16; ++k) {
            s  += ((const float*)&lsum [k][tid>>2])[tid&3];
            ss += ((const float*)&lssum[k][tid>>2])[tid&3];
        }
        psum[tid*1536 + b] = s;
        pss [tid*1536 + b] = ss;
    }
}

// reduce partials -> mean / rsqrt(var)
__global__ void k_stats2(const float* __restrict__ psum, const float* __restrict__ pss,
                         float* __restrict__ stats) {
    int u = blockIdx.x;               // 0..127
    int n = u >> 6, c = u & 63;
    int l = threadIdx.x;              // 0..63
    float s = 0.f, ss = 0.f;
    #pragma unroll
    for (int k = 0; k < 12; ++k) {
        int row = n*768 + k*64 + l;
        s  += psum[c*1536 + row];
        ss += pss [c*1536 + row];
    }
    #pragma unroll
    for (int o2 = 32; o2 >= 1; o2 >>= 1) {
        s  += __shfl_xor(s, o2);
        ss += __shfl_xor(ss, o2);
    }
    if (l == 0) {
        float inv = 1.f / (float)S_;
        float mean = s * inv;
        float var = ss * inv - mean*mean;
        stats[n*128 + c] = mean;
        stats[n*128 + 64 + c] = rsqrtf(var + 1e-5f);
    }
}

// fused DCN + output GEMM: block = 1z x 4y x 8x = 32 voxels (64 pairs)
// 2b uses inline-asm global loads + counted vmcnt so prefetch survives codegen
__global__ __launch_bounds__(256, 2) void k_dcn(const unsigned short* __restrict__ xprojP,
        const float* __restrict__ dw, const float* __restrict__ stats,
        const unsigned short* __restrict__ wBg, const float4* __restrict__ b4f,
        const unsigned short* __restrict__ W2T, const float* __restrict__ B2,
        const float* __restrict__ xin, const float* __restrict__ gate,
        float* __restrict__ out) {
    __shared__ uint4 descW[27][64];     // phase1: float4 offs; phase2: f16 weight pairs
    __shared__ union {
        unsigned short featB[32][64];   // 1a/1b: bf16 feat (swizzled 16B blocks)
        int cwl[27][64];                // 2a/2b: base element offsets
        unsigned short coreT[32][64];   // phase4: f16 core (swizzled 16B blocks)
    } uS;
    int tid = threadIdx.x;
    // bijective XCD swizzle: 4608 blocks = 8 * 576
    int orig = blockIdx.x;
    int bid = (orig & 7) * 576 + (orig >> 3);
    int x8 = bid % 12;
    int t1 = bid / 12;
    int y4 = t1 % 24;
    int t2 = t1 / 24;                 // 0..15
    int z  = t2 & 7;
    int n  = t2 >> 3;
    int yb = y4*4, xb = x8*8;
    size_t voxBase = (size_t)n*S_ + (size_t)z*HW_ + yb*W_ + xb;
    float4* offsF = (float4*)descW;

    // 1a: feat = gelu(instnorm(dw)) -> bf16 featB[vox][k] (swizzled 16B blocks)
    {
        int c4 = (tid & 15) * 4;
        int vp = tid >> 4;
        #pragma unroll
        for (int j = 0; j < 2; ++j) {
            int vloc = vp*2 + j;
            size_t vox = voxBase + (vloc>>3)*W_ + (vloc & 7);
            float4 v = *(const float4*)&dw[vox*64 + c4];
            float vals[4] = {v.x, v.y, v.z, v.w};
            ushort4 pk;
            unsigned short* pp = (unsigned short*)&pk;
            #pragma unroll
            for (int jj = 0; jj < 4; ++jj) {
                int c = c4 + jj;
                float t = (vals[jj] - stats[n*128+c]) * stats[n*128+64+c];
                pp[jj] = f2bf(gelu_fast(t));
            }
            int off = ((((c4 >> 3) ^ (vloc & 7)) << 3) | (c4 & 7));
            *(ushort4*)&uS.featB[vloc][off] = pk;
        }
    }
    __syncthreads();

    // 1b: MFMA projection. D[224][32] = wBg[224x64] @ featB[64x32]
    {
        int w = tid >> 6;
        int l = tid & 63;
        int lr = l & 15;
        int lq = l >> 4;
        for (int i = 0; i < 7; ++i) {
            int t7 = w*7 + i;
            int mt = t7 >> 1, nt = t7 & 1;
            int vox = nt*16 + lr;
            f32x4 acc = {0.f, 0.f, 0.f, 0.f};
            #pragma unroll
            for (int h = 0; h < 2; ++h) {
                int k0 = h*32 + lq*8;
                short8 af = *(const short8*)&wBg[(mt*16 + lr)*64 + k0];
                int blk = (((k0 >> 3) ^ (vox & 7)) << 3);
                short8 bf = *(const short8*)&uS.featB[vox][blk];
                acc = __builtin_amdgcn_mfma_f32_16x16x32_bf16(af, bf, acc, 0, 0, 0);
            }
            int u = mt*4 + lq;
            if (u < 54) {
                float4 bb = b4f[u];
                int g = (u >= 27) ? 1 : 0;
                int p = u - g*27;
                offsF[p*64 + vox*2 + g] = make_float4(acc[0] + bb.x, acc[1] + bb.y,
                                                      acc[2] + bb.z, acc[3] + bb.w);
            }
        }
    }
    __syncthreads();

    // softmax over taps per pair (64 pairs); logits in regs, write .w dword only
    if (tid < 64) {
        int pair = tid;
        float lg[27];
        float mx = -1e30f;
        #pragma unroll
        for (int p = 0; p < 27; ++p) {
            lg[p] = offsF[p*64 + pair].w;
            mx = fmaxf(mx, lg[p]);
        }
        float ssum = 0.f;
        #pragma unroll
        for (int p = 0; p < 27; ++p) { lg[p] = __expf(lg[p] - mx); ssum += lg[p]; }
        float inv = __builtin_amdgcn_rcpf(ssum);
        #pragma unroll
        for (int p = 0; p < 27; ++p)
            offsF[p*64 + pair].w = lg[p]*inv;
    }
    __syncthreads();

    // 2a: tap descriptors — 4 packed f16 weight pairs + base offset, once per (pair,tap)
    {
        int zm1 = z - 1;
        #pragma unroll
        for (int k = 0; k < 7; ++k) {
            int idx = tid + k*256;
            if (idx < 1728) {
                int pair = idx & 63;
                int p = idx >> 6;
                float4 tp = offsF[p*64 + pair];
                int vloc = pair >> 1, g = pair & 1;
                int yy = vloc >> 3, xx = vloc & 7;
                float zf = (float)(zm1 + p/9) + tp.z;
                float yf = (float)(yb + yy - 1 + (p/3)%3) + tp.y;
                float xf = (float)(xb + xx - 1 + p%3) + tp.x;
                zf = fminf(fmaxf(zf, -1.5f), (float)D_ + 0.5f);
                yf = fminf(fmaxf(yf, -1.5f), (float)H_ + 0.5f);
                xf = fminf(fmaxf(xf, -1.5f), (float)W_ + 0.5f);
                float z0f = floorf(zf), y0f = floorf(yf), x0f = floorf(xf);
                float fz = zf - z0f, fy = yf - y0f, fx = xf - x0f;
                int zi = (int)z0f, yi = (int)y0f, xi = (int)x0f;
                float wz1 = fz * tp.w, wz0 = tp.w - wz1;   // prob folded in
                float wy1 = fy, wy0 = 1.f - fy;
                float wx1 = fx, wx0 = 1.f - fx;
                float w00 = wz0*wy0, w01 = wz0*wy1, w10 = wz1*wy0, w11 = wz1*wy1;
                unsigned u0 = h2AsU(__builtin_amdgcn_cvt_pkrtz(w00*wx0, w00*wx1));
                unsigned u1 = h2AsU(__builtin_amdgcn_cvt_pkrtz(w01*wx0, w01*wx1));
                unsigned u2 = h2AsU(__builtin_amdgcn_cvt_pkrtz(w10*wx0, w10*wx1));
                unsigned u3 = h2AsU(__builtin_amdgcn_cvt_pkrtz(w11*wx0, w11*wx1));
                int cw = zi*ZS_ + yi*YS_ + (xi<<6) + (2*ZS_ + 2*YS_ + 128) + g*32;
                descW[p][pair] = make_uint4(u0, u1, u2, u3);
                uS.cwl[p][pair] = cw;
            }
        }
    }
    __syncthreads();

    // 2b: asm-prefetched gather — issue tap p+1's 8 loads, vmcnt(8) gates tap p
    int pair = tid >> 2;              // 0..63
    int vloc = pair >> 1, g = pair & 1;
    int ch4 = (tid & 3) * 8;          // channel offset within group
    const unsigned short* __restrict__ base = xprojP + (size_t)n*NSTR_ + ch4;
    float a0=0.f,a1=0.f,a2=0.f,a3=0.f,a4=0.f,a5=0.f,a6=0.f,a7=0.f;

    uint4 wpA, wpB;
    u32x4 qa0A, qa1A, qb0A, qb1A, qc0A, qc1A, qd0A, qd1A;
    u32x4 qa0B, qa1B, qb0B, qb1B, qc0B, qc1B, qd0B, qd1B;

    #define GLD0(d, a)   asm volatile("global_load_dwordx4 %0, %1, off" \
                                      : "=v"(d) : "v"(a))
    #define GLD128(d, a) asm volatile("global_load_dwordx4 %0, %1, off offset:128" \
                                      : "=v"(d) : "v"(a))
    #define LOADT(P, SFX) { \
        wp##SFX = descW[(P)][pair]; \
        int cw_ = uS.cwl[(P)][pair]; \
        const unsigned short* p00_ = base + cw_; \
        const unsigned short* p01_ = p00_ + YS_; \
        const unsigned short* p10_ = p00_ + ZS_; \
        const unsigned short* p11_ = p10_ + YS_; \
        GLD0(qa0##SFX, p00_);  GLD128(qa1##SFX, p00_); \
        GLD0(qb0##SFX, p01_);  GLD128(qb1##SFX, p01_); \
        GLD0(qc0##SFX, p10_);  GLD128(qc1##SFX, p10_); \
        GLD0(qd0##SFX, p11_);  GLD128(qd1##SFX, p11_); \
    }
    #define WAITV8 { asm volatile("s_waitcnt vmcnt(8)"); \
                     __builtin_amdgcn_sched_barrier(0); }
    #define WAITV0 { asm volatile("s_waitcnt vmcnt(0)"); \
                     __builtin_amdgcn_sched_barrier(0); }
    // perm sel: lo-ch pair = {A.b0,A.b1,B.b0,B.b1} -> 0x01000504 ; hi-ch -> 0x03020706
    #define CP(QA, QB, WH) { \
        a0 = dot2f(__builtin_amdgcn_perm(QA[0], QB[0], 0x01000504u), WH, a0); \
        a1 = dot2f(__builtin_amdgcn_perm(QA[0], QB[0], 0x03020706u), WH, a1); \
        a2 = dot2f(__builtin_amdgcn_perm(QA[1], QB[1], 0x01000504u), WH, a2); \
        a3 = dot2f(__builtin_amdgcn_perm(QA[1], QB[1], 0x03020706u), WH, a3); \
        a4 = dot2f(__builtin_amdgcn_perm(QA[2], QB[2], 0x01000504u), WH, a4); \
        a5 = dot2f(__builtin_amdgcn_perm(QA[2], QB[2], 0x03020706u), WH, a5); \
        a6 = dot2f(__builtin_amdgcn_perm(QA[3], QB[3], 0x01000504u), WH, a6); \
        a7 = dot2f(__builtin_amdgcn_perm(QA[3], QB[3], 0x03020706u), WH, a7); \
    }
    #define COMPT(SFX) { \
        h2 w0_ = uAsH2(wp##SFX.x), w1_ = uAsH2(wp##SFX.y); \
        h2 w2_ = uAsH2(wp##SFX.z), w3_ = uAsH2(wp##SFX.w); \
        CP(qa0##SFX, qa1##SFX, w0_); CP(qb0##SFX, qb1##SFX, w1_); \
        CP(qc0##SFX, qc1##SFX, w2_); CP(qd0##SFX, qd1##SFX, w3_); \
    }

    LOADT(0, A);
    #pragma unroll 1
    for (int p = 0; p < 26; p += 2) {
        LOADT(p+1, B);
        WAITV8;
        COMPT(A);
        LOADT(p+2, A);
        WAITV8;
        COMPT(B);
    }
    WAITV0;
    COMPT(A);   // tap 26
    #undef COMPT
    #undef CP
    #undef WAITV0
    #undef WAITV8
    #undef LOADT
    #undef GLD128
    #undef GLD0
    __syncthreads();   // done reading cwl; reuse union as coreT

    // 3: pack core to f16 into coreT[vox][c] (swizzled 16B blocks)
    {
        unsigned c01 = h2AsU(__builtin_amdgcn_cvt_pkrtz(a0, a1));
        unsigned c23 = h2AsU(__builtin_amdgcn_cvt_pkrtz(a2, a3));
        unsigned c45 = h2AsU(__builtin_amdgcn_cvt_pkrtz(a4, a5));
        unsigned c67 = h2AsU(__builtin_amdgcn_cvt_pkrtz(a6, a7));
        int col = g*32 + ch4;
        int blk = (((col >> 3) ^ (vloc & 7)) << 3);
        *(uint4*)&uS.coreT[vloc][blk] = make_uint4(c01, c23, c45, c67);
    }
    __syncthreads();

    // 4: output GEMM via MFMA: out[32 vox][64 o] = coreT @ W2T^T ; +bias, +residual
    {
        int w = tid >> 6, l = tid & 63, lr = l & 15, lq = l >> 4;
        float sg = 1.f / (1.f + __expf(-gate[0]));
        #pragma unroll
        for (int t = 0; t < 2; ++t) {
            int tile = w*2 + t;
            int mt = tile >> 2, nt = tile & 3;
            int o = nt*16 + lr;
            f32x4 acc = {0.f, 0.f, 0.f, 0.f};
            #pragma unroll
            for (int h = 0; h < 2; ++h) {
                int k0 = h*32 + lq*8;
                int arow = mt*16 + lr;
                int blk = (((k0 >> 3) ^ (arow & 7)) << 3);
                short8 af = *(const short8*)&uS.coreT[arow][blk];
                short8 bf = *(const short8*)&W2T[o*64 + k0];
                acc = __builtin_amdgcn_mfma_f32_16x16x32_f16(af, bf, acc, 0, 0, 0);
            }
            float b2 = B2[o];
            int vox0 = mt*16 + lq*4;
            int yy = vox0 >> 3, xx0 = vox0 & 7;
            size_t gi = ((size_t)(n*64 + o))*S_ + (size_t)z*HW_ + (size_t)(yb+yy)*W_ + (xb+xx0);
            float4 xv = *(const float4*)&xin[gi];
            float4 r;
            r.x = fmaf(sg, acc[0] + b2, xv.x);
            r.y = fmaf(sg, acc[1] + b2, xv.y);
            r.z = fmaf(sg, acc[2] + b2, xv.z);
            r.w = fmaf(sg, acc[3] + b2, xv.w);
            *(float4*)&out[gi] = r;
        }
    }
}

extern "C" void kernel_launch(void* const* d_in, const int* in_sizes, int n_in,
                              void* d_out, int out_size, void* d_ws, size_t ws_size,
                              hipStream_t stream) {
    const float* x      = (const float*)d_in[0];
    const float* w_pre  = (const float*)d_in[1];
    const float* w_in   = (const float*)d_in[2];
    const float* b_in   = (const float*)d_in[3];
    const float* w_dw   = (const float*)d_in[4];
    const float* w_off  = (const float*)d_in[5];
    const float* b_off  = (const float*)d_in[6];
    const float* w_mask = (const float*)d_in[7];
    const float* b_mask = (const float*)d_in[8];
    const float* w_out  = (const float*)d_in[9];
    const float* b_out  = (const float*)d_in[10];
    const float* w_post = (const float*)d_in[11];
    const float* gate   = (const float*)d_in[12];
    float* out = (float*)d_out;

    float* ws      = (float*)d_ws;
    unsigned short* xprojP = (unsigned short*)ws;      // 15,360,000 ushorts (30.7MB)
    float* pre     = ws + (size_t)7680000;             // 9,437,184 floats
    float* dwb     = pre + (size_t)9437184;            // 9,437,184 floats (dw scratch)
    float* psum    = dwb + (size_t)9437184;            // 98,304
    float* pss     = psum + 98304;                     // 98,304
    float* stats   = pss + 98304;                      // 256
    float* B2      = stats + 256;                      // 64 (+pad)
    unsigned short* W2T = (unsigned short*)(B2 + 128); // 64*64 ushorts
    unsigned short* wBg = W2T + 4096;                  // 224*64 ushorts
    float4* b4f    = (float4*)(wBg + 14336 + 64);      // 54 float4

    (void)hipMemsetAsync(xprojP, 0, (size_t)15360000*sizeof(unsigned short), stream);
    hipLaunchKernelGGL(k_prep,     dim3(64),   dim3(64),  0, stream,
                       w_out, b_out, w_post, w_off, b_off, w_mask, b_mask,
                       B2, W2T, wBg, b4f);
    hipLaunchKernelGGL(k_pre_proj, dim3(2304), dim3(256), 0, stream,
                       x, w_pre, w_in, b_in, pre, xprojP);
    hipLaunchKernelGGL(k_dw_stats, dim3(1536), dim3(256), 0, stream,
                       pre, w_dw, dwb, psum, pss);
    hipLaunchKernelGGL(k_stats2,   dim3(128),  dim3(64),  0, stream, psum, pss, stats);
    hipLaunchKernelGGL(k_dcn,      dim3(4608), dim3(256), 0, stream,
                       xprojP, dwb, stats, wBg, b4f, W2T, B2, x, gate, out);
}

// Round 17
// 304.015 us; speedup vs baseline: 1.0294x; 1.0049x over previous
//
#include <hip/hip_runtime.h>
#include <math.h>

#define N_ 2
#define C_ 64
#define D_ 8
#define H_ 96
#define W_ 96
#define S_ (D_*H_*W_)   // 73728
#define HW_ (H_*W_)     // 9216
// padded xproj (f16): [n][z+2 of 12][y+2 of 100][x+2 of 100][64]
#define ZP_ 12
#define YP_ 100
#define XP_ 100
#define NSTR_ (ZP_*YP_*XP_*64)   // 7680000 elements
#define ZS_ (YP_*XP_*64)         // 640000
#define YS_ (XP_*64)             // 6400

typedef __attribute__((ext_vector_type(8))) short short8;
typedef __attribute__((ext_vector_type(4))) float f32x4;
typedef __attribute__((ext_vector_type(2))) __fp16 h2;
typedef __attribute__((ext_vector_type(4))) unsigned u32x4;

union U32H2 { unsigned u; h2 h; unsigned short s[2]; };
__device__ __forceinline__ h2 uAsH2(unsigned u){ U32H2 t; t.u = u; return t.h; }
__device__ __forceinline__ unsigned h2AsU(h2 h){ U32H2 t; t.h = h; return t.u; }

__device__ __forceinline__ float dot2f(unsigned u, h2 w, float acc) {
#if __has_builtin(__builtin_amdgcn_fdot2)
    return __builtin_amdgcn_fdot2(uAsH2(u), w, acc, false);
#else
    h2 v = uAsH2(u);
    return fmaf((float)v.y, (float)w.y, fmaf((float)v.x, (float)w.x, acc));
#endif
}

__device__ __forceinline__ float gelu_fast(float x) {
    float a = 0.7978845608028654f * (x + 0.044715f*x*x*x);
    float E = __expf(2.f*a);
    return x - x * __builtin_amdgcn_rcpf(E + 1.f);
}

__device__ __forceinline__ unsigned short f2bf(float f) {   // RNE bf16
    unsigned u = __float_as_uint(f);
    unsigned r = (u + 0x7fffu + ((u >> 16) & 1u)) >> 16;
    return (unsigned short)r;
}

__device__ __forceinline__ unsigned short f2h(float f) {    // f32 -> f16 bits
    U32H2 t; t.h[0] = (__fp16)f; t.h[1] = (__fp16)0.f; return t.s[0];
}

// prep: W2 = w_out @ w_post^T (f16-transposed), B2; wBg bf16 proj weights; b4f biases
__global__ __launch_bounds__(64) void k_prep(const float* __restrict__ w_out,
        const float* __restrict__ b_out, const float* __restrict__ w_post,
        const float* __restrict__ w_off, const float* __restrict__ b_off,
        const float* __restrict__ w_mask, const float* __restrict__ b_mask,
        float* __restrict__ B2, unsigned short* __restrict__ W2T,
        unsigned short* __restrict__ wBg, float4* __restrict__ b4f) {
    int b = blockIdx.x;      // 0..63  (= core-channel c2)
    int t = threadIdx.x;     // 0..63  (= output o)
    float acc = 0.f;
    for (int c = 0; c < 64; ++c)
        acc = fmaf(w_out[b*64+c], w_post[t*64+c], acc);
    W2T[t*64 + b] = f2h(acc);          // W2T[o][c2] f16
    if (b == 0) {
        float a2 = 0.f;
        for (int c = 0; c < 64; ++c)
            a2 = fmaf(w_post[t*64+c], b_out[c], a2);
        B2[t] = a2;
    }
    {
        int c = b;
        for (int m = t; m < 224; m += 64) {
            float v = 0.f;
            if (m < 216) {
                int u = m >> 2, comp = m & 3;
                if (comp == 3) v = w_mask[c*54 + u];
                else {
                    v = w_off[c*162 + u*3 + comp];
                    if (comp == 0) v *= 0.5f;
                }
            }
            wBg[m*64 + c] = f2bf(v);
        }
    }
    if (b == 1 && t < 54)
        b4f[t] = make_float4(b_off[t*3]*0.5f, b_off[t*3+1], b_off[t*3+2], b_mask[t]);
}

// fused: pre = x @ w_pre^T (fp32, for dw), xprojP = f16(pre @ w_in + b_in) padded
__global__ __launch_bounds__(256) void k_pre_proj(const float* __restrict__ x,
        const float* __restrict__ w_pre, const float* __restrict__ w_in,
        const float* __restrict__ b_in, float* __restrict__ pre,
        unsigned short* __restrict__ xprojP) {
    __shared__ float lx[64][65];    // [c][v] then reused as [v][c2]
    __shared__ float lwa[64][65];   // w_pre [o][c]
    __shared__ float lwb[64][65];   // w_in  [c][o]
    int b = blockIdx.x;
    int n = b / 1152;
    int s0 = (b % 1152) * 64;
    int tid = threadIdx.x;
    for (int idx = tid; idx < 1024; idx += 256) {
        int r = idx >> 4, q4 = (idx & 15) * 4;
        float4 vx = *(const float4*)&x[((size_t)(n*C_ + r))*S_ + s0 + q4];
        lx[r][q4] = vx.x; lx[r][q4+1] = vx.y; lx[r][q4+2] = vx.z; lx[r][q4+3] = vx.w;
        float4 va = *(const float4*)&w_pre[r*64 + q4];
        lwa[r][q4] = va.x; lwa[r][q4+1] = va.y; lwa[r][q4+2] = va.z; lwa[r][q4+3] = va.w;
        float4 vb = *(const float4*)&w_in[r*64 + q4];
        lwb[r][q4] = vb.x; lwb[r][q4+1] = vb.y; lwb[r][q4+2] = vb.z; lwb[r][q4+3] = vb.w;
    }
    __syncthreads();
    int o0 = (tid & 15) * 4;
    int v0 = (tid >> 4) * 4;
    float acc[4][4] = {};
    #pragma unroll 8
    for (int c = 0; c < 64; ++c) {
        float xv[4], wv[4];
        #pragma unroll
        for (int j = 0; j < 4; ++j) { xv[j] = lx[c][v0+j]; wv[j] = lwa[o0+j][c]; }
        #pragma unroll
        for (int vj = 0; vj < 4; ++vj)
            #pragma unroll
            for (int oj = 0; oj < 4; ++oj)
                acc[vj][oj] = fmaf(xv[vj], wv[oj], acc[vj][oj]);
    }
    #pragma unroll
    for (int vj = 0; vj < 4; ++vj) {
        float4 r = make_float4(acc[vj][0], acc[vj][1], acc[vj][2], acc[vj][3]);
        *(float4*)&pre[((size_t)(n*S_ + s0 + v0 + vj))*64 + o0] = r;
    }
    __syncthreads();
    #pragma unroll
    for (int vj = 0; vj < 4; ++vj)
        #pragma unroll
        for (int oj = 0; oj < 4; ++oj)
            lx[v0+vj][o0+oj] = acc[vj][oj];   // lx = pre tile [v][c2]
    __syncthreads();
    float acc2[4][4];
    #pragma unroll
    for (int oj = 0; oj < 4; ++oj) {
        float bo = b_in[o0+oj];
        #pragma unroll
        for (int vj = 0; vj < 4; ++vj) acc2[vj][oj] = bo;
    }
    #pragma unroll 8
    for (int c = 0; c < 64; ++c) {
        float fv[4], wv[4];
        #pragma unroll
        for (int j = 0; j < 4; ++j) { fv[j] = lx[v0+j][c]; wv[j] = lwb[c][o0+j]; }
        #pragma unroll
        for (int vj = 0; vj < 4; ++vj)
            #pragma unroll
            for (int oj = 0; oj < 4; ++oj)
                acc2[vj][oj] = fmaf(fv[vj], wv[oj], acc2[vj][oj]);
    }
    #pragma unroll
    for (int vj = 0; vj < 4; ++vj) {
        int vox = s0 + v0 + vj;      // within image n
        int z = vox / HW_;
        int rem = vox - z*HW_;
        int y = rem / W_;
        int xq = rem - y*W_;
        size_t pw = (size_t)n*NSTR_ + (size_t)(z+2)*ZS_ + (y+2)*YS_ + (xq+2)*64 + o0;
        unsigned lo = h2AsU(__builtin_amdgcn_cvt_pkrtz(acc2[vj][0], acc2[vj][1]));
        unsigned hi = h2AsU(__builtin_amdgcn_cvt_pkrtz(acc2[vj][2], acc2[vj][3]));
        *(uint2*)&xprojP[pw] = make_uint2(lo, hi);
    }
}

// depthwise 3x3x3 + instance-norm partials; 4 channels per thread, float4 loads
__global__ __launch_bounds__(256) void k_dw_stats(const float* __restrict__ pre,
        const float* __restrict__ w_dw, float* __restrict__ dw,
        float* __restrict__ psum, float* __restrict__ pss) {
    __shared__ float4 lwd[27][16];     // [tap][c4]
    __shared__ float4 lsum[16][16];    // [xg][c4]
    __shared__ float4 lssum[16][16];
    int b = blockIdx.x;               // n*D*H + z*H + y  (1536)
    int y = b % H_;
    int z = (b / H_) % D_;
    int n = b / (D_*H_);
    int tid = threadIdx.x;
    if (tid < 27*16) {
        int k = tid >> 4, c4 = tid & 15;
        lwd[k][c4] = make_float4(w_dw[(c4*4+0)*27 + k], w_dw[(c4*4+1)*27 + k],
                                 w_dw[(c4*4+2)*27 + k], w_dw[(c4*4+3)*27 + k]);
    }
    __syncthreads();
    int c4 = tid & 15, xg = tid >> 4;
    const float* preN = pre + (size_t)n*S_*64;
    float4 s4 = make_float4(0,0,0,0), ss4 = make_float4(0,0,0,0);
    for (int xx = 0; xx < 6; ++xx) {
        int xi = xg + xx*16;
        float4 acc = make_float4(0,0,0,0);
        #pragma unroll
        for (int dz = 0; dz < 3; ++dz) {
            int zz = z + dz - 1;
            if (zz < 0 || zz >= D_) continue;
            #pragma unroll
            for (int dy = 0; dy < 3; ++dy) {
                int yy = y + dy - 1;
                if (yy < 0 || yy >= H_) continue;
                int rowb = (zz*HW_ + yy*W_)*64 + c4*4;
                #pragma unroll
                for (int dx = 0; dx < 3; ++dx) {
                    int xn = xi + dx - 1;
                    if ((unsigned)xn < (unsigned)W_) {
                        float4 v = *(const float4*)&preN[rowb + (xn<<6)];
                        float4 w = lwd[dz*9+dy*3+dx][c4];
                        acc.x = fmaf(v.x, w.x, acc.x);
                        acc.y = fmaf(v.y, w.y, acc.y);
                        acc.z = fmaf(v.z, w.z, acc.z);
                        acc.w = fmaf(v.w, w.w, acc.w);
                    }
                }
            }
        }
        *(float4*)&dw[((size_t)n*S_ + z*HW_ + y*W_ + xi)*64 + c4*4] = acc;
        s4.x += acc.x; s4.y += acc.y; s4.z += acc.z; s4.w += acc.w;
        ss4.x = fmaf(acc.x, acc.x, ss4.x); ss4.y = fmaf(acc.y, acc.y, ss4.y);
        ss4.z = fmaf(acc.z, acc.z, ss4.z); ss4.w = fmaf(acc.w, acc.w, ss4.w);
    }
    lsum[xg][c4] = s4; lssum[xg][c4] = ss4;
    __syncthreads();
    if (tid < 64) {
        float s = 0.f, ss = 0.f;
        #pragma unroll
        for (int k = 0; k < 16; ++k) {
            s  += ((const float*)&lsum [k][tid>>2])[tid&3];
            ss += ((const float*)&lssum[k][tid>>2])[tid&3];
        }
        psum[tid*1536 + b] = s;
        pss [tid*1536 + b] = ss;
    }
}

// reduce partials -> mean / rsqrt(var)
__global__ void k_stats2(const float* __restrict__ psum, const float* __restrict__ pss,
                         float* __restrict__ stats) {
    int u = blockIdx.x;               // 0..127
    int n = u >> 6, c = u & 63;
    int l = threadIdx.x;              // 0..63
    float s = 0.f, ss = 0.f;
    #pragma unroll
    for (int k = 0; k < 12; ++k) {
        int row = n*768 + k*64 + l;
        s  += psum[c*1536 + row];
        ss += pss [c*1536 + row];
    }
    #pragma unroll
    for (int o2 = 32; o2 >= 1; o2 >>= 1) {
        s  += __shfl_xor(s, o2);
        ss += __shfl_xor(ss, o2);
    }
    if (l == 0) {
        float inv = 1.f / (float)S_;
        float mean = s * inv;
        float var = ss * inv - mean*mean;
        stats[n*128 + c] = mean;
        stats[n*128 + 64 + c] = rsqrtf(var + 1e-5f);
    }
}

// fused DCN + output GEMM: block = 1z x 4y x 8x = 32 voxels (64 pairs)
// 2b: 3-deep asm-prefetched gather (A/B/C rotation, vmcnt(16) gates oldest)
__global__ __launch_bounds__(256, 2) void k_dcn(const unsigned short* __restrict__ xprojP,
        const float* __restrict__ dw, const float* __restrict__ stats,
        const unsigned short* __restrict__ wBg, const float4* __restrict__ b4f,
        const unsigned short* __restrict__ W2T, const float* __restrict__ B2,
        const float* __restrict__ xin, const float* __restrict__ gate,
        float* __restrict__ out) {
    __shared__ uint4 descW[27][64];     // phase1: float4 offs; phase2: f16 weight pairs
    __shared__ union {
        unsigned short featB[32][64];   // 1a/1b: bf16 feat (swizzled 16B blocks)
        int cwl[27][64];                // 2a/2b: base element offsets
        unsigned short coreT[32][64];   // phase4: f16 core (swizzled 16B blocks)
    } uS;
    int tid = threadIdx.x;
    // bijective XCD swizzle: 4608 blocks = 8 * 576
    int orig = blockIdx.x;
    int bid = (orig & 7) * 576 + (orig >> 3);
    int x8 = bid % 12;
    int t1 = bid / 12;
    int y4 = t1 % 24;
    int t2 = t1 / 24;                 // 0..15
    int z  = t2 & 7;
    int n  = t2 >> 3;
    int yb = y4*4, xb = x8*8;
    size_t voxBase = (size_t)n*S_ + (size_t)z*HW_ + yb*W_ + xb;
    float4* offsF = (float4*)descW;

    // 1a: feat = gelu(instnorm(dw)) -> bf16 featB[vox][k] (swizzled 16B blocks)
    {
        int c4 = (tid & 15) * 4;
        int vp = tid >> 4;
        #pragma unroll
        for (int j = 0; j < 2; ++j) {
            int vloc = vp*2 + j;
            size_t vox = voxBase + (vloc>>3)*W_ + (vloc & 7);
            float4 v = *(const float4*)&dw[vox*64 + c4];
            float vals[4] = {v.x, v.y, v.z, v.w};
            ushort4 pk;
            unsigned short* pp = (unsigned short*)&pk;
            #pragma unroll
            for (int jj = 0; jj < 4; ++jj) {
                int c = c4 + jj;
                float t = (vals[jj] - stats[n*128+c]) * stats[n*128+64+c];
                pp[jj] = f2bf(gelu_fast(t));
            }
            int off = ((((c4 >> 3) ^ (vloc & 7)) << 3) | (c4 & 7));
            *(ushort4*)&uS.featB[vloc][off] = pk;
        }
    }
    __syncthreads();

    // 1b: MFMA projection. D[224][32] = wBg[224x64] @ featB[64x32]
    {
        int w = tid >> 6;
        int l = tid & 63;
        int lr = l & 15;
        int lq = l >> 4;
        for (int i = 0; i < 7; ++i) {
            int t7 = w*7 + i;
            int mt = t7 >> 1, nt = t7 & 1;
            int vox = nt*16 + lr;
            f32x4 acc = {0.f, 0.f, 0.f, 0.f};
            #pragma unroll
            for (int h = 0; h < 2; ++h) {
                int k0 = h*32 + lq*8;
                short8 af = *(const short8*)&wBg[(mt*16 + lr)*64 + k0];
                int blk = (((k0 >> 3) ^ (vox & 7)) << 3);
                short8 bf = *(const short8*)&uS.featB[vox][blk];
                acc = __builtin_amdgcn_mfma_f32_16x16x32_bf16(af, bf, acc, 0, 0, 0);
            }
            int u = mt*4 + lq;
            if (u < 54) {
                float4 bb = b4f[u];
                int g = (u >= 27) ? 1 : 0;
                int p = u - g*27;
                offsF[p*64 + vox*2 + g] = make_float4(acc[0] + bb.x, acc[1] + bb.y,
                                                      acc[2] + bb.z, acc[3] + bb.w);
            }
        }
    }
    __syncthreads();

    // softmax over taps per pair (64 pairs); logits in regs, write .w dword only
    if (tid < 64) {
        int pair = tid;
        float lg[27];
        float mx = -1e30f;
        #pragma unroll
        for (int p = 0; p < 27; ++p) {
            lg[p] = offsF[p*64 + pair].w;
            mx = fmaxf(mx, lg[p]);
        }
        float ssum = 0.f;
        #pragma unroll
        for (int p = 0; p < 27; ++p) { lg[p] = __expf(lg[p] - mx); ssum += lg[p]; }
        float inv = __builtin_amdgcn_rcpf(ssum);
        #pragma unroll
        for (int p = 0; p < 27; ++p)
            offsF[p*64 + pair].w = lg[p]*inv;
    }
    __syncthreads();

    // 2a: tap descriptors — 4 packed f16 weight pairs + base offset, once per (pair,tap)
    {
        int zm1 = z - 1;
        #pragma unroll
        for (int k = 0; k < 7; ++k) {
            int idx = tid + k*256;
            if (idx < 1728) {
                int pair = idx & 63;
                int p = idx >> 6;
                float4 tp = offsF[p*64 + pair];
                int vloc = pair >> 1, g = pair & 1;
                int yy = vloc >> 3, xx = vloc & 7;
                float zf = (float)(zm1 + p/9) + tp.z;
                float yf = (float)(yb + yy - 1 + (p/3)%3) + tp.y;
                float xf = (float)(xb + xx - 1 + p%3) + tp.x;
                zf = fminf(fmaxf(zf, -1.5f), (float)D_ + 0.5f);
                yf = fminf(fmaxf(yf, -1.5f), (float)H_ + 0.5f);
                xf = fminf(fmaxf(xf, -1.5f), (float)W_ + 0.5f);
                float z0f = floorf(zf), y0f = floorf(yf), x0f = floorf(xf);
                float fz = zf - z0f, fy = yf - y0f, fx = xf - x0f;
                int zi = (int)z0f, yi = (int)y0f, xi = (int)x0f;
                float wz1 = fz * tp.w, wz0 = tp.w - wz1;   // prob folded in
                float wy1 = fy, wy0 = 1.f - fy;
                float wx1 = fx, wx0 = 1.f - fx;
                float w00 = wz0*wy0, w01 = wz0*wy1, w10 = wz1*wy0, w11 = wz1*wy1;
                unsigned u0 = h2AsU(__builtin_amdgcn_cvt_pkrtz(w00*wx0, w00*wx1));
                unsigned u1 = h2AsU(__builtin_amdgcn_cvt_pkrtz(w01*wx0, w01*wx1));
                unsigned u2 = h2AsU(__builtin_amdgcn_cvt_pkrtz(w10*wx0, w10*wx1));
                unsigned u3 = h2AsU(__builtin_amdgcn_cvt_pkrtz(w11*wx0, w11*wx1));
                int cw = zi*ZS_ + yi*YS_ + (xi<<6) + (2*ZS_ + 2*YS_ + 128) + g*32;
                descW[p][pair] = make_uint4(u0, u1, u2, u3);
                uS.cwl[p][pair] = cw;
            }
        }
    }
    __syncthreads();

    // 2b: 3-deep asm-prefetched gather
    int pair = tid >> 2;              // 0..63
    int vloc = pair >> 1, g = pair & 1;
    int ch4 = (tid & 3) * 8;          // channel offset within group
    const unsigned short* __restrict__ base = xprojP + (size_t)n*NSTR_ + ch4;
    float a0=0.f,a1=0.f,a2=0.f,a3=0.f,a4=0.f,a5=0.f,a6=0.f,a7=0.f;

    uint4 wpA, wpB, wpC;
    u32x4 qa0A, qa1A, qb0A, qb1A, qc0A, qc1A, qd0A, qd1A;
    u32x4 qa0B, qa1B, qb0B, qb1B, qc0B, qc1B, qd0B, qd1B;
    u32x4 qa0C, qa1C, qb0C, qb1C, qc0C, qc1C, qd0C, qd1C;

    #define GLD0(d, a)   asm volatile("global_load_dwordx4 %0, %1, off" \
                                      : "=v"(d) : "v"(a))
    #define GLD128(d, a) asm volatile("global_load_dwordx4 %0, %1, off offset:128" \
                                      : "=v"(d) : "v"(a))
    #define LOADT(P, SFX) { \
        wp##SFX = descW[(P)][pair]; \
        int cw_ = uS.cwl[(P)][pair]; \
        const unsigned short* p00_ = base + cw_; \
        const unsigned short* p01_ = p00_ + YS_; \
        const unsigned short* p10_ = p00_ + ZS_; \
        const unsigned short* p11_ = p10_ + YS_; \
        GLD0(qa0##SFX, p00_);  GLD128(qa1##SFX, p00_); \
        GLD0(qb0##SFX, p01_);  GLD128(qb1##SFX, p01_); \
        GLD0(qc0##SFX, p10_);  GLD128(qc1##SFX, p10_); \
        GLD0(qd0##SFX, p11_);  GLD128(qd1##SFX, p11_); \
    }
    #define WAITV(N) { asm volatile("s_waitcnt vmcnt(" #N ")"); \
                       __builtin_amdgcn_sched_barrier(0); }
    // perm sel: lo-ch pair = {A.b0,A.b1,B.b0,B.b1} -> 0x01000504 ; hi-ch -> 0x03020706
    #define CP(QA, QB, WH) { \
        a0 = dot2f(__builtin_amdgcn_perm(QA[0], QB[0], 0x01000504u), WH, a0); \
        a1 = dot2f(__builtin_amdgcn_perm(QA[0], QB[0], 0x03020706u), WH, a1); \
        a2 = dot2f(__builtin_amdgcn_perm(QA[1], QB[1], 0x01000504u), WH, a2); \
        a3 = dot2f(__builtin_amdgcn_perm(QA[1], QB[1], 0x03020706u), WH, a3); \
        a4 = dot2f(__builtin_amdgcn_perm(QA[2], QB[2], 0x01000504u), WH, a4); \
        a5 = dot2f(__builtin_amdgcn_perm(QA[2], QB[2], 0x03020706u), WH, a5); \
        a6 = dot2f(__builtin_amdgcn_perm(QA[3], QB[3], 0x01000504u), WH, a6); \
        a7 = dot2f(__builtin_amdgcn_perm(QA[3], QB[3], 0x03020706u), WH, a7); \
    }
    #define COMPT(SFX) { \
        h2 w0_ = uAsH2(wp##SFX.x), w1_ = uAsH2(wp##SFX.y); \
        h2 w2_ = uAsH2(wp##SFX.z), w3_ = uAsH2(wp##SFX.w); \
        CP(qa0##SFX, qa1##SFX, w0_); CP(qb0##SFX, qb1##SFX, w1_); \
        CP(qc0##SFX, qc1##SFX, w2_); CP(qd0##SFX, qd1##SFX, w3_); \
    }

    LOADT(0, A);
    LOADT(1, B);
    #pragma unroll 1
    for (int p = 0; p < 24; p += 3) {
        LOADT(p+2, C);
        WAITV(16);
        COMPT(A);
        LOADT(p+3, A);
        WAITV(16);
        COMPT(B);
        LOADT(p+4, B);
        WAITV(16);
        COMPT(C);
    }
    // remaining: A=24, B=25 in flight
    LOADT(26, C);
    WAITV(16);
    COMPT(A);
    WAITV(8);
    COMPT(B);
    WAITV(0);
    COMPT(C);
    #undef COMPT
    #undef CP
    #undef WAITV
    #undef LOADT
    #undef GLD128
    #undef GLD0
    __syncthreads();   // done reading cwl; reuse union as coreT

    // 3: pack core to f16 into coreT[vox][c] (swizzled 16B blocks)
    {
        unsigned c01 = h2AsU(__builtin_amdgcn_cvt_pkrtz(a0, a1));
        unsigned c23 = h2AsU(__builtin_amdgcn_cvt_pkrtz(a2, a3));
        unsigned c45 = h2AsU(__builtin_amdgcn_cvt_pkrtz(a4, a5));
        unsigned c67 = h2AsU(__builtin_amdgcn_cvt_pkrtz(a6, a7));
        int col = g*32 + ch4;
        int blk = (((col >> 3) ^ (vloc & 7)) << 3);
        *(uint4*)&uS.coreT[vloc][blk] = make_uint4(c01, c23, c45, c67);
    }
    __syncthreads();

    // 4: output GEMM via MFMA: out[32 vox][64 o] = coreT @ W2T^T ; +bias, +residual
    {
        int w = tid >> 6, l = tid & 63, lr = l & 15, lq = l >> 4;
        float sg = 1.f / (1.f + __expf(-gate[0]));
        #pragma unroll
        for (int t = 0; t < 2; ++t) {
            int tile = w*2 + t;
            int mt = tile >> 2, nt = tile & 3;
            int o = nt*16 + lr;
            f32x4 acc = {0.f, 0.f, 0.f, 0.f};
            #pragma unroll
            for (int h = 0; h < 2; ++h) {
                int k0 = h*32 + lq*8;
                int arow = mt*16 + lr;
                int blk = (((k0 >> 3) ^ (arow & 7)) << 3);
                short8 af = *(const short8*)&uS.coreT[arow][blk];
                short8 bf = *(const short8*)&W2T[o*64 + k0];
                acc = __builtin_amdgcn_mfma_f32_16x16x32_f16(af, bf, acc, 0, 0, 0);
            }
            float b2 = B2[o];
            int vox0 = mt*16 + lq*4;
            int yy = vox0 >> 3, xx0 = vox0 & 7;
            size_t gi = ((size_t)(n*64 + o))*S_ + (size_t)z*HW_ + (size_t)(yb+yy)*W_ + (xb+xx0);
            float4 xv = *(const float4*)&xin[gi];
            float4 r;
            r.x = fmaf(sg, acc[0] + b2, xv.x);
            r.y = fmaf(sg, acc[1] + b2, xv.y);
            r.z = fmaf(sg, acc[2] + b2, xv.z);
            r.w = fmaf(sg, acc[3] + b2, xv.w);
            *(float4*)&out[gi] = r;
        }
    }
}

extern "C" void kernel_launch(void* const* d_in, const int* in_sizes, int n_in,
                              void* d_out, int out_size, void* d_ws, size_t ws_size,
                              hipStream_t stream) {
    const float* x      = (const float*)d_in[0];
    const float* w_pre  = (const float*)d_in[1];
    const float* w_in   = (const float*)d_in[2];
    const float* b_in   = (const float*)d_in[3];
    const float* w_dw   = (const float*)d_in[4];
    const float* w_off  = (const float*)d_in[5];
    const float* b_off  = (const float*)d_in[6];
    const float* w_mask = (const float*)d_in[7];
    const float* b_mask = (const float*)d_in[8];
    const float* w_out  = (const float*)d_in[9];
    const float* b_out  = (const float*)d_in[10];
    const float* w_post = (const float*)d_in[11];
    const float* gate   = (const float*)d_in[12];
    float* out = (float*)d_out;

    float* ws      = (float*)d_ws;
    unsigned short* xprojP = (unsigned short*)ws;      // 15,360,000 ushorts (30.7MB)
    float* pre     = ws + (size_t)7680000;             // 9,437,184 floats
    float* dwb     = pre + (size_t)9437184;            // 9,437,184 floats (dw scratch)
    float* psum    = dwb + (size_t)9437184;            // 98,304
    float* pss     = psum + 98304;                     // 98,304
    float* stats   = pss + 98304;                      // 256
    float* B2      = stats + 256;                      // 64 (+pad)
    unsigned short* W2T = (unsigned short*)(B2 + 128); // 64*64 ushorts
    unsigned short* wBg = W2T + 4096;                  // 224*64 ushorts
    float4* b4f    = (float4*)(wBg + 14336 + 64);      // 54 float4

    (void)hipMemsetAsync(xprojP, 0, (size_t)15360000*sizeof(unsigned short), stream);
    hipLaunchKernelGGL(k_prep,     dim3(64),   dim3(64),  0, stream,
                       w_out, b_out, w_post, w_off, b_off, w_mask, b_mask,
                       B2, W2T, wBg, b4f);
    hipLaunchKernelGGL(k_pre_proj, dim3(2304), dim3(256), 0, stream,
                       x, w_pre, w_in, b_in, pre, xprojP);
    hipLaunchKernelGGL(k_dw_stats, dim3(1536), dim3(256), 0, stream,
                       pre, w_dw, dwb, psum, pss);
    hipLaunchKernelGGL(k_stats2,   dim3(128),  dim3(64),  0, stream, psum, pss, stats);
    hipLaunchKernelGGL(k_dcn,      dim3(4608), dim3(256), 0, stream,
                       xprojP, dwb, stats, wBg, b4f, W2T, B2, x, gate, out);
}